// Round 1
// baseline (2680.177 us; speedup 1.0000x reference)
//
#include <hip/hip_runtime.h>
#include <math.h>

#define Bb 128
#define Tt 128
#define Dd 128
#define Nn 128
#define Mm 128
#define Hh 256
#define NT 512
#define EPSF 1e-8f

__device__ __forceinline__ float softplusf(float v) {
  return (v > 20.f) ? v : log1pf(expf(v));
}
__device__ __forceinline__ float sigmoidf(float v) {
  return 1.f / (1.f + expf(-v));
}

__global__ __launch_bounds__(NT, 1) void ntm_kernel(
    const float* __restrict__ x, const float* __restrict__ mem0,
    const float* __restrict__ wr0, const float* __restrict__ ww0,
    const float* __restrict__ h0, const float* __restrict__ Wx,
    const float* __restrict__ Wrd, const float* __restrict__ bh,
    const float* __restrict__ Wk, const float* __restrict__ bk,
    const float* __restrict__ Wb, const float* __restrict__ bb,
    const float* __restrict__ Wg, const float* __restrict__ bg,
    const float* __restrict__ Ws, const float* __restrict__ bs,
    const float* __restrict__ Wgam, const float* __restrict__ bgam,
    const float* __restrict__ We, const float* __restrict__ be,
    const float* __restrict__ Wa, const float* __restrict__ ba,
    float* __restrict__ out) {
  const int b = blockIdx.x;
  const int t = threadIdx.x;

  __shared__ float mem[Nn * Mm];     // 64 KB: the per-batch NTM memory
  __shared__ float h[Hh];
  __shared__ float wr[Nn], ww[Nn];
  __shared__ float er[Mm], ad[Mm];
  __shared__ float rvec[Mm];
  __shared__ float normsq[Nn];
  __shared__ float dotv[Nn];
  __shared__ float wgbuf[Nn];
  __shared__ float kbuf[2 * Mm];
  __shared__ float part[NT];
  __shared__ float scal[16];
  __shared__ float red[8];

  for (int i = t; i < Nn * Mm; i += NT) mem[i] = mem0[i];
  for (int i = t; i < Nn; i += NT) { wr[i] = wr0[b * Nn + i]; ww[i] = ww0[b * Nn + i]; }
  for (int i = t; i < Hh; i += NT) h[i] = h0[b * Hh + i];
  __syncthreads();

  for (int step = 0; step < Tt; ++step) {
    // ---- Phase A: erase = sigmoid(h@We+be), add = tanh(h@Wa+ba) (uses OLD h)
    {
      const int o = t & 255;
      const int jh = t >> 8;
      const int m = o & 127;
      const float* W = (o < 128) ? We : Wa;
      const float* Wp = W + (jh * 128) * Mm + m;
      const float* hp = h + jh * 128;
      float a0 = 0.f, a1 = 0.f, a2 = 0.f, a3 = 0.f;
      #pragma unroll 8
      for (int j = 0; j < 128; j += 4) {
        a0 += hp[j]     * Wp[(j)     * Mm];
        a1 += hp[j + 1] * Wp[(j + 1) * Mm];
        a2 += hp[j + 2] * Wp[(j + 2) * Mm];
        a3 += hp[j + 3] * Wp[(j + 3) * Mm];
      }
      part[t] = (a0 + a1) + (a2 + a3);
    }
    __syncthreads();
    if (t < 256) {
      const int m = t & 127;
      float v = part[t] + part[t + 256];
      if (t < 128) er[m] = sigmoidf(v + be[m]);
      else         ad[m] = tanhf(v + ba[m]);
    }
    __syncthreads();

    // ---- Phase B: mem = mem*(1 - ww*erase) + ww*add ; row normsq
    // rotated index -> <=2-way LDS bank aliasing (free)
    {
      const int n = t >> 2, q = t & 3;
      const float wwn = ww[n];
      float* row = mem + n * Mm;
      float nrm = 0.f;
      #pragma unroll
      for (int j = 0; j < 32; ++j) {
        const int m = q * 32 + ((j + n + q * 8) & 31);
        float v = row[m];
        v = v * (1.f - wwn * er[m]) + wwn * ad[m];
        row[m] = v;
        nrm += v * v;
      }
      nrm += __shfl_xor(nrm, 1);
      nrm += __shfl_xor(nrm, 2);
      if (q == 0) normsq[n] = nrm;
    }
    __syncthreads();

    // ---- Phase R: r[m] = sum_n wr[n]*mem[n][m]
    {
      const int m = t & 127, nq = t >> 7;
      float a0 = 0.f, a1 = 0.f;
      #pragma unroll 8
      for (int j = 0; j < 32; j += 2) {
        const int n0 = nq * 32 + j;
        a0 += wr[n0]     * mem[n0 * Mm + m];
        a1 += wr[n0 + 1] * mem[(n0 + 1) * Mm + m];
      }
      part[t] = a0 + a1;
    }
    __syncthreads();
    if (t < 128) rvec[t] = (part[t] + part[t + 128]) + (part[t + 256] + part[t + 384]);
    __syncthreads();

    // ---- Phase C: h = tanh(x_t@Wx + r@Wrd + bh)  (writes NEW h)
    {
      const int i = t & 255, half = t >> 8;
      const float* src = half ? rvec : (x + ((size_t)b * Tt + step) * Dd);
      const float* W = half ? (Wrd + i) : (Wx + i);
      float a0 = 0.f, a1 = 0.f, a2 = 0.f, a3 = 0.f;
      #pragma unroll 8
      for (int j = 0; j < 128; j += 4) {
        a0 += src[j]     * W[(j)     * Hh];
        a1 += src[j + 1] * W[(j + 1) * Hh];
        a2 += src[j + 2] * W[(j + 2) * Hh];
        a3 += src[j + 3] * W[(j + 3) * Hh];
      }
      part[t] = (a0 + a1) + (a2 + a3);
    }
    __syncthreads();
    if (t < 256) {
      float v = tanhf(part[t] + part[t + 256] + bh[t]);
      h[t] = v;
      out[((size_t)b * Tt + step) * Hh + t] = v;
    }
    __syncthreads();

    // ---- small dots: beta, g, gamma, s-logits for both heads (12 dots over H)
    {
      const int lane = t & 63, w = t >> 6;
      for (int d = w; d < 12; d += 8) {
        const int head = d / 6, kind = d % 6;
        const float* Wp;
        int stride;
        if (kind == 0)      { Wp = Wb + head * Hh;                 stride = 1; }
        else if (kind == 1) { Wp = Wg + head * Hh;                 stride = 1; }
        else if (kind == 2) { Wp = Wgam + head * Hh;               stride = 1; }
        else                { Wp = Ws + head * Hh * 3 + (kind - 3); stride = 3; }
        float acc = 0.f;
        #pragma unroll
        for (int j = lane; j < Hh; j += 64) acc += h[j] * Wp[j * stride];
        acc += __shfl_xor(acc, 32); acc += __shfl_xor(acc, 16);
        acc += __shfl_xor(acc, 8);  acc += __shfl_xor(acc, 4);
        acc += __shfl_xor(acc, 2);  acc += __shfl_xor(acc, 1);
        if (lane == 0) {
          float v;
          if (kind == 0)      v = softplusf(acc + bb[head]);
          else if (kind == 1) v = sigmoidf(acc + bg[head]);
          else if (kind == 2) v = 1.f + softplusf(acc + bgam[head]);
          else                v = acc + bs[head * 3 + (kind - 3)];
          scal[head * 8 + kind] = v;
        }
      }
    }
    __syncthreads();
    if (t < 2) {  // softmax over the 3 shift logits, per head
      float e0 = scal[t * 8 + 3], e1 = scal[t * 8 + 4], e2 = scal[t * 8 + 5];
      float mx = fmaxf(e0, fmaxf(e1, e2));
      float x0 = expf(e0 - mx), x1 = expf(e1 - mx), x2 = expf(e2 - mx);
      float si = x0 + x1 + x2;
      scal[t * 8 + 3] = x0 / si; scal[t * 8 + 4] = x1 / si; scal[t * 8 + 5] = x2 / si;
    }

    // ---- Phase D: k = tanh(h@Wk+bk), both heads
    {
      const int o = t & 255, jh = t >> 8;
      const int head = o >> 7, m = o & 127;
      const float* Wp = Wk + head * Hh * Mm + (jh * 128) * Mm + m;
      const float* hp = h + jh * 128;
      float a0 = 0.f, a1 = 0.f, a2 = 0.f, a3 = 0.f;
      #pragma unroll 8
      for (int j = 0; j < 128; j += 4) {
        a0 += hp[j]     * Wp[(j)     * Mm];
        a1 += hp[j + 1] * Wp[(j + 1) * Mm];
        a2 += hp[j + 2] * Wp[(j + 2) * Mm];
        a3 += hp[j + 3] * Wp[(j + 3) * Mm];
      }
      part[t] = (a0 + a1) + (a2 + a3);
    }
    __syncthreads();
    if (t < 256) kbuf[t] = tanhf(part[t] + part[t + 256] + bk[t]);
    __syncthreads();

    // ---- ||k|| per head
    {
      float v = 0.f;
      if (t < 256) { float kk = kbuf[t]; v = kk * kk; }
      v += __shfl_xor(v, 32); v += __shfl_xor(v, 16); v += __shfl_xor(v, 8);
      v += __shfl_xor(v, 4);  v += __shfl_xor(v, 2);  v += __shfl_xor(v, 1);
      if (t < 256 && (t & 63) == 0) red[t >> 6] = v;
    }
    __syncthreads();
    if (t < 2) scal[t * 8 + 6] = sqrtf(red[2 * t] + red[2 * t + 1]);
    __syncthreads();

    // ---- per-head content+location addressing
    for (int head = 0; head < 2; ++head) {
      const float* kh = kbuf + head * 128;
      float* wprev = head ? ww : wr;
      {
        const int n = t >> 2, q = t & 3;
        const float* row = mem + n * Mm;
        float acc = 0.f;
        #pragma unroll
        for (int j = 0; j < 32; ++j) {
          const int m = q * 32 + ((j + n + q * 8) & 31);
          acc += kh[m] * row[m];
        }
        acc += __shfl_xor(acc, 1);
        acc += __shfl_xor(acc, 2);
        if (q == 0) dotv[n] = acc;
      }
      __syncthreads();
      const float beta  = scal[head * 8 + 0], g = scal[head * 8 + 1];
      const float gamma = scal[head * 8 + 2];
      const float s0 = scal[head * 8 + 3], s1 = scal[head * 8 + 4], s2 = scal[head * 8 + 5];
      const float knorm = scal[head * 8 + 6];
      float logit = -3.4e38f;
      if (t < 128) logit = beta * (dotv[t] / (knorm * sqrtf(normsq[t]) + EPSF));
      float mx = logit;
      mx = fmaxf(mx, __shfl_xor(mx, 32)); mx = fmaxf(mx, __shfl_xor(mx, 16));
      mx = fmaxf(mx, __shfl_xor(mx, 8));  mx = fmaxf(mx, __shfl_xor(mx, 4));
      mx = fmaxf(mx, __shfl_xor(mx, 2));  mx = fmaxf(mx, __shfl_xor(mx, 1));
      if (t < 128 && (t & 63) == 0) red[t >> 6] = mx;
      __syncthreads();
      const float gmax = fmaxf(red[0], red[1]);
      float e = 0.f;
      if (t < 128) e = expf(logit - gmax);
      float sm = e;
      sm += __shfl_xor(sm, 32); sm += __shfl_xor(sm, 16); sm += __shfl_xor(sm, 8);
      sm += __shfl_xor(sm, 4);  sm += __shfl_xor(sm, 2);  sm += __shfl_xor(sm, 1);
      if (t < 128 && (t & 63) == 0) red[2 + (t >> 6)] = sm;
      __syncthreads();
      const float gsum = red[2] + red[3];
      if (t < 128) wgbuf[t] = g * (e / gsum) + (1.f - g) * wprev[t];
      __syncthreads();
      float wp = 0.f;
      if (t < 128) {
        const float sh = s0 * wgbuf[(t + 127) & 127] + s1 * wgbuf[t]
                       + s2 * wgbuf[(t + 1) & 127];
        wp = powf(sh, gamma);
      }
      float ps = wp;
      ps += __shfl_xor(ps, 32); ps += __shfl_xor(ps, 16); ps += __shfl_xor(ps, 8);
      ps += __shfl_xor(ps, 4);  ps += __shfl_xor(ps, 2);  ps += __shfl_xor(ps, 1);
      if (t < 128 && (t & 63) == 0) red[4 + (t >> 6)] = ps;
      __syncthreads();
      const float tot = red[4] + red[5] + EPSF;
      if (t < 128) wprev[t] = wp / tot;
      __syncthreads();
    }
  }
}

extern "C" void kernel_launch(void* const* d_in, const int* in_sizes, int n_in,
                              void* d_out, int out_size, void* d_ws, size_t ws_size,
                              hipStream_t stream) {
  const float* x    = (const float*)d_in[0];
  const float* mem0 = (const float*)d_in[1];
  const float* wr0  = (const float*)d_in[2];
  const float* ww0  = (const float*)d_in[3];
  const float* h0   = (const float*)d_in[4];
  const float* Wx   = (const float*)d_in[5];
  const float* Wrd  = (const float*)d_in[6];
  const float* bh   = (const float*)d_in[7];
  const float* Wk   = (const float*)d_in[8];
  const float* bk   = (const float*)d_in[9];
  const float* Wb   = (const float*)d_in[10];
  const float* bb   = (const float*)d_in[11];
  const float* Wg   = (const float*)d_in[12];
  const float* bg   = (const float*)d_in[13];
  const float* Ws   = (const float*)d_in[14];
  const float* bs   = (const float*)d_in[15];
  const float* Wgam = (const float*)d_in[16];
  const float* bgam = (const float*)d_in[17];
  const float* We   = (const float*)d_in[18];
  const float* be   = (const float*)d_in[19];
  const float* Wa   = (const float*)d_in[20];
  const float* ba   = (const float*)d_in[21];
  float* out = (float*)d_out;

  hipLaunchKernelGGL(ntm_kernel, dim3(Bb), dim3(NT), 0, stream,
                     x, mem0, wr0, ww0, h0, Wx, Wrd, bh, Wk, bk, Wb, bb,
                     Wg, bg, Ws, bs, Wgam, bgam, We, be, Wa, ba, out);
}